// Round 1
// baseline (221.537 us; speedup 1.0000x reference)
//
#include <hip/hip_runtime.h>
#include <math.h>

#define DD 768
#define NN 64
#define SS 512
#define BB 4

__device__ __forceinline__ float sigmf(float v) { return 1.0f / (1.0f + expf(-v)); }

// ---- DPP full-wave (64-lane) sum; result valid in lane 63 ----
template <int CTRL>
__device__ __forceinline__ float dppadd(float v) {
    int s = __builtin_amdgcn_update_dpp(0, __float_as_int(v), CTRL, 0xF, 0xF, true);
    return v + __int_as_float(s);
}
__device__ __forceinline__ float wave_sum63(float v) {
    v = dppadd<0x111>(v);  // row_shr:1
    v = dppadd<0x112>(v);  // row_shr:2
    v = dppadd<0x114>(v);  // row_shr:4
    v = dppadd<0x118>(v);  // row_shr:8
    v = dppadd<0x142>(v);  // row_bcast:15
    v = dppadd<0x143>(v);  // row_bcast:31
    return v;              // lane 63 holds the full 64-lane sum
}

// ---- prep: BwT[d][n] = sigmoid(Braw[n][d]); gamma_s = sigmoid(gamma_raw) ----
__global__ __launch_bounds__(256) void prep_kernel(const float* __restrict__ Braw,
                                                   const float* __restrict__ graw,
                                                   float* __restrict__ BwT,
                                                   float* __restrict__ gamma_s) {
    int i = blockIdx.x * 256 + threadIdx.x;
    if (i < DD * NN) {
        int d = i / NN, n = i - d * NN;
        BwT[i] = sigmf(Braw[n * DD + d]);
    }
    if (i < DD) gamma_s[i] = sigmf(graw[i]);
}

// ---- phase 1: inp[r][n] = sum_d x[r][d] * BwT[d][n], r in [0, B*S) ----
__global__ __launch_bounds__(256) void inp_kernel(const float* __restrict__ x,
                                                  const float* __restrict__ BwT,
                                                  float* __restrict__ inp) {
    int wid  = (blockIdx.x * 256 + threadIdx.x) >> 6;  // row 0..2047
    int lane = threadIdx.x & 63;
    const float* xr = x + (size_t)wid * DD;
    float acc = 0.f;
#pragma unroll 8
    for (int d = 0; d < DD; ++d)
        acc = fmaf(xr[d], BwT[d * NN + lane], acc);
    inp[wid * NN + lane] = acc;
}

// ---- phase 2: per-(b,d) wave scan over t; writes pre-norm y into Y, h_final ----
__global__ __launch_bounds__(256) void scan_kernel(const float* __restrict__ x,
                                                   const float* __restrict__ Araw,
                                                   const float* __restrict__ Craw,
                                                   const float* __restrict__ inp,
                                                   float* __restrict__ Y,
                                                   float* __restrict__ hfin) {
    int wid  = (blockIdx.x * 256 + threadIdx.x) >> 6;  // 0..3071
    int lane = threadIdx.x & 63;                       // n
    int b = wid / DD;
    int d = wid - b * DD;

    float a = sigmf(Araw[d * NN + lane]);
    float c = sigmf(Craw[d * NN + lane]);

    const float* ip_ptr = inp + (size_t)(b * SS) * NN + lane;
    const float* x_ptr  = x   + (size_t)(b * SS) * DD + d;
    float*       y_ptr  = Y   + (size_t)(b * SS) * DD + d;

    float h = 0.f;
#pragma unroll 8
    for (int t = 0; t < SS; ++t) {
        float ip = ip_ptr[(size_t)t * NN];      // coalesced across lanes
        float xv = x_ptr[(size_t)t * DD];       // wave-uniform broadcast
        h = fmaf(h, a, ip * xv);
        h = fminf(fmaxf(h, 0.f), 1.f);
        float v = wave_sum63(h * c);
        if (lane == 63) y_ptr[(size_t)t * DD] = v;
    }
    hfin[(size_t)(b * DD + d) * NN + lane] = h;
}

// ---- phase 3: in-place layernorm + gamma + residual + clip ----
__global__ __launch_bounds__(256) void ln_kernel(const float* __restrict__ x,
                                                 const float* __restrict__ gamma_s,
                                                 float* __restrict__ out) {
    int wid  = (blockIdx.x * 256 + threadIdx.x) >> 6;  // row 0..2047
    int lane = threadIdx.x & 63;
    const float* yr = out + (size_t)wid * DD;
    const float* xr = x   + (size_t)wid * DD;

    float yv[12];
    float s = 0.f;
#pragma unroll
    for (int i = 0; i < 12; ++i) {
        yv[i] = yr[lane * 12 + i];
        s += yv[i];
    }
#pragma unroll
    for (int off = 32; off; off >>= 1) s += __shfl_xor(s, off, 64);
    float mu = s * (1.f / 768.f);

    float q = 0.f;
#pragma unroll
    for (int i = 0; i < 12; ++i) {
        float d0 = yv[i] - mu;
        q = fmaf(d0, d0, q);
    }
#pragma unroll
    for (int off = 32; off; off >>= 1) q += __shfl_xor(q, off, 64);
    float inv = rsqrtf(q * (1.f / 768.f) + 1e-5f);

#pragma unroll
    for (int i = 0; i < 12; ++i) {
        int dcol = lane * 12 + i;
        float val = (yv[i] - mu) * inv * gamma_s[dcol] + xr[dcol];
        out[(size_t)wid * DD + dcol] = fminf(fmaxf(val, 0.f), 1.f);
    }
}

extern "C" void kernel_launch(void* const* d_in, const int* in_sizes, int n_in,
                              void* d_out, int out_size, void* d_ws, size_t ws_size,
                              hipStream_t stream) {
    const float* x    = (const float*)d_in[0];  // [B,S,D]
    const float* Araw = (const float*)d_in[1];  // [D,N]
    const float* Braw = (const float*)d_in[2];  // [N,D]
    const float* Craw = (const float*)d_in[3];  // [D,N]
    const float* graw = (const float*)d_in[4];  // [D]

    float* out  = (float*)d_out;                // [B,S,D] then [B,D,N]
    float* hfin = out + (size_t)BB * SS * DD;

    float* ws      = (float*)d_ws;
    float* BwT     = ws;                         // D*N   = 49152
    float* gamma_s = ws + DD * NN;               // D     = 768
    float* inp     = ws + DD * NN + DD;          // B*S*N = 131072

    prep_kernel<<<(DD * NN + 255) / 256, 256, 0, stream>>>(Braw, graw, BwT, gamma_s);
    inp_kernel<<<(BB * SS * NN) / 256, 256, 0, stream>>>(x, BwT, inp);
    scan_kernel<<<(BB * DD * NN) / 256, 256, 0, stream>>>(x, Araw, Craw, inp, out, hfin);
    ln_kernel<<<(BB * SS * NN) / 256, 256, 0, stream>>>(x, gamma_s, out);
}

// Round 2
// 102.810 us; speedup vs baseline: 2.1548x; 2.1548x over previous
//
#include <hip/hip_runtime.h>
#include <math.h>

#define DD 768
#define NN 64
#define SS 512
#define BB 4
#define PF 8

__device__ __forceinline__ float sigmf(float v) { return 1.0f / (1.0f + expf(-v)); }

// ---- DPP full-wave (64-lane) sum; result valid in lane 63 ----
template <int CTRL>
__device__ __forceinline__ float dppadd(float v) {
    int s = __builtin_amdgcn_update_dpp(0, __float_as_int(v), CTRL, 0xF, 0xF, true);
    return v + __int_as_float(s);
}
__device__ __forceinline__ float wave_sum63(float v) {
    v = dppadd<0x111>(v);  // row_shr:1
    v = dppadd<0x112>(v);  // row_shr:2
    v = dppadd<0x114>(v);  // row_shr:4
    v = dppadd<0x118>(v);  // row_shr:8
    v = dppadd<0x142>(v);  // row_bcast:15
    v = dppadd<0x143>(v);  // row_bcast:31
    return v;              // lane 63 holds the full 64-lane sum
}

// ---- prep: BwT[d][n] = sigmoid(Braw[n][d]); gamma_s = sigmoid(gamma_raw) ----
__global__ __launch_bounds__(256) void prep_kernel(const float* __restrict__ Braw,
                                                   const float* __restrict__ graw,
                                                   float* __restrict__ BwT,
                                                   float* __restrict__ gamma_s) {
    int i = blockIdx.x * 256 + threadIdx.x;
    if (i < DD * NN) {
        int d = i / NN, n = i - d * NN;
        BwT[i] = sigmf(Braw[n * DD + d]);
    }
    if (i < DD) gamma_s[i] = sigmf(graw[i]);
}

// ---- phase 1: inp[r][n] = sum_d x[r][d] * BwT[d][n], r in [0, B*S) ----
// One wave per row. Double-buffered chunks of 16 d-values:
// x via broadcast float4 loads, BwT via coalesced per-lane loads.
__global__ __launch_bounds__(256) void inp_kernel(const float* __restrict__ x,
                                                  const float* __restrict__ BwT,
                                                  float* __restrict__ inp) {
    int wid  = (blockIdx.x * 256 + threadIdx.x) >> 6;  // row 0..2047
    int lane = threadIdx.x & 63;
    const float4* xr4 = (const float4*)(x + (size_t)wid * DD);
    const float*  bp  = BwT + lane;

    float xc[16], xn[16], bwc[16], bwn[16];

#define LOADX(dst, base4)                                        \
    {                                                            \
        float4 q0 = xr4[(base4) + 0], q1 = xr4[(base4) + 1];     \
        float4 q2 = xr4[(base4) + 2], q3 = xr4[(base4) + 3];     \
        dst[0] = q0.x; dst[1] = q0.y; dst[2] = q0.z; dst[3] = q0.w;   \
        dst[4] = q1.x; dst[5] = q1.y; dst[6] = q1.z; dst[7] = q1.w;   \
        dst[8] = q2.x; dst[9] = q2.y; dst[10] = q2.z; dst[11] = q2.w; \
        dst[12] = q3.x; dst[13] = q3.y; dst[14] = q3.z; dst[15] = q3.w; \
    }

    LOADX(xc, 0);
#pragma unroll
    for (int i = 0; i < 16; ++i) bwc[i] = bp[i * NN];

    float acc0 = 0.f, acc1 = 0.f, acc2 = 0.f, acc3 = 0.f;
    for (int d0 = 0; d0 < DD; d0 += 16) {
        int dn = (d0 + 16 < DD) ? (d0 + 16) : 0;  // clamped (redundant last prefetch)
        LOADX(xn, dn >> 2);
#pragma unroll
        for (int i = 0; i < 16; ++i) bwn[i] = bp[(dn + i) * NN];
#pragma unroll
        for (int i = 0; i < 16; i += 4) {
            acc0 = fmaf(xc[i + 0], bwc[i + 0], acc0);
            acc1 = fmaf(xc[i + 1], bwc[i + 1], acc1);
            acc2 = fmaf(xc[i + 2], bwc[i + 2], acc2);
            acc3 = fmaf(xc[i + 3], bwc[i + 3], acc3);
        }
#pragma unroll
        for (int i = 0; i < 16; ++i) { xc[i] = xn[i]; bwc[i] = bwn[i]; }
    }
    inp[wid * NN + lane] = (acc0 + acc1) + (acc2 + acc3);
}

// ---- phase 2: per-(b,d) wave scan over t; software-pipelined loads ----
__global__ __launch_bounds__(256) void scan_kernel(const float* __restrict__ x,
                                                   const float* __restrict__ Araw,
                                                   const float* __restrict__ Craw,
                                                   const float* __restrict__ inp,
                                                   float* __restrict__ Y,
                                                   float* __restrict__ hfin) {
    int wid  = (blockIdx.x * 256 + threadIdx.x) >> 6;  // 0..3071
    int lane = threadIdx.x & 63;                       // n
    int b = wid / DD;
    int d = wid - b * DD;

    float a = sigmf(Araw[d * NN + lane]);
    float c = sigmf(Craw[d * NN + lane]);

    const float* ip_ptr = inp + (b * SS) * NN + lane;
    const float* x_ptr  = x   + (b * SS) * DD + d;
    float*       y_ptr  = Y   + (b * SS) * DD + d;

    float cip[PF], cxv[PF], nip[PF], nxv[PF];
#pragma unroll
    for (int i = 0; i < PF; ++i) {
        cip[i] = ip_ptr[i * NN];
        cxv[i] = x_ptr[i * DD];
    }

    float h = 0.f;
    for (int t0 = 0; t0 < SS; t0 += PF) {
        int tn = t0 + PF;
        if (tn >= SS) tn = SS - PF;  // uniform; final prefetch is redundant but in-bounds
        // issue next-chunk loads (independent of h-chain)
#pragma unroll
        for (int i = 0; i < PF; ++i) {
            nip[i] = ip_ptr[(tn + i) * NN];
            nxv[i] = x_ptr[(tn + i) * DD];
        }
        // compute current chunk: only h is loop-carried (fma + med3)
#pragma unroll
        for (int i = 0; i < PF; ++i) {
            h = __builtin_amdgcn_fmed3f(fmaf(h, a, cip[i] * cxv[i]), 0.f, 1.f);
            float v = wave_sum63(h * c);
            if (lane == 63) y_ptr[(t0 + i) * DD] = v;
        }
#pragma unroll
        for (int i = 0; i < PF; ++i) { cip[i] = nip[i]; cxv[i] = nxv[i]; }
    }
    hfin[(size_t)wid * NN + lane] = h;
}

// ---- phase 3: in-place layernorm + gamma + residual + clip (float4) ----
__global__ __launch_bounds__(256) void ln_kernel(const float* __restrict__ x,
                                                 const float* __restrict__ gamma_s,
                                                 float* __restrict__ out) {
    int wid  = (blockIdx.x * 256 + threadIdx.x) >> 6;  // row 0..2047
    int lane = threadIdx.x & 63;
    float*       yr = out + (size_t)wid * DD;
    const float* xr = x   + (size_t)wid * DD;

    float4 y0 = ((const float4*)yr)[lane * 3 + 0];
    float4 y1 = ((const float4*)yr)[lane * 3 + 1];
    float4 y2 = ((const float4*)yr)[lane * 3 + 2];

    float s = ((y0.x + y0.y) + (y0.z + y0.w)) + ((y1.x + y1.y) + (y1.z + y1.w)) +
              ((y2.x + y2.y) + (y2.z + y2.w));
#pragma unroll
    for (int off = 32; off; off >>= 1) s += __shfl_xor(s, off, 64);
    float mu = s * (1.f / 768.f);

    float q = 0.f;
#define QACC(v)                         \
    {                                   \
        float d0_ = (v) - mu;           \
        q = fmaf(d0_, d0_, q);          \
    }
    QACC(y0.x) QACC(y0.y) QACC(y0.z) QACC(y0.w)
    QACC(y1.x) QACC(y1.y) QACC(y1.z) QACC(y1.w)
    QACC(y2.x) QACC(y2.y) QACC(y2.z) QACC(y2.w)
#pragma unroll
    for (int off = 32; off; off >>= 1) q += __shfl_xor(q, off, 64);
    float inv = rsqrtf(q * (1.f / 768.f) + 1e-5f);

    float4 g0 = ((const float4*)gamma_s)[lane * 3 + 0];
    float4 g1 = ((const float4*)gamma_s)[lane * 3 + 1];
    float4 g2 = ((const float4*)gamma_s)[lane * 3 + 2];
    float4 x0 = ((const float4*)xr)[lane * 3 + 0];
    float4 x1 = ((const float4*)xr)[lane * 3 + 1];
    float4 x2 = ((const float4*)xr)[lane * 3 + 2];

#define FIN(yv, gv, xv) __builtin_amdgcn_fmed3f(fmaf((yv - mu) * inv, gv, xv), 0.f, 1.f)
    float4 o0, o1, o2;
    o0.x = FIN(y0.x, g0.x, x0.x); o0.y = FIN(y0.y, g0.y, x0.y);
    o0.z = FIN(y0.z, g0.z, x0.z); o0.w = FIN(y0.w, g0.w, x0.w);
    o1.x = FIN(y1.x, g1.x, x1.x); o1.y = FIN(y1.y, g1.y, x1.y);
    o1.z = FIN(y1.z, g1.z, x1.z); o1.w = FIN(y1.w, g1.w, x1.w);
    o2.x = FIN(y2.x, g2.x, x2.x); o2.y = FIN(y2.y, g2.y, x2.y);
    o2.z = FIN(y2.z, g2.z, x2.z); o2.w = FIN(y2.w, g2.w, x2.w);

    ((float4*)yr)[lane * 3 + 0] = o0;
    ((float4*)yr)[lane * 3 + 1] = o1;
    ((float4*)yr)[lane * 3 + 2] = o2;
}

extern "C" void kernel_launch(void* const* d_in, const int* in_sizes, int n_in,
                              void* d_out, int out_size, void* d_ws, size_t ws_size,
                              hipStream_t stream) {
    const float* x    = (const float*)d_in[0];  // [B,S,D]
    const float* Araw = (const float*)d_in[1];  // [D,N]
    const float* Braw = (const float*)d_in[2];  // [N,D]
    const float* Craw = (const float*)d_in[3];  // [D,N]
    const float* graw = (const float*)d_in[4];  // [D]

    float* out  = (float*)d_out;                // [B,S,D] then [B,D,N]
    float* hfin = out + (size_t)BB * SS * DD;

    float* ws      = (float*)d_ws;
    float* BwT     = ws;                         // D*N   = 49152
    float* gamma_s = ws + DD * NN;               // D     = 768
    float* inp     = ws + DD * NN + DD;          // B*S*N = 131072

    prep_kernel<<<(DD * NN + 255) / 256, 256, 0, stream>>>(Braw, graw, BwT, gamma_s);
    inp_kernel<<<(BB * SS * NN) / 256, 256, 0, stream>>>(x, BwT, inp);
    scan_kernel<<<(BB * DD * NN) / 256, 256, 0, stream>>>(x, Araw, Craw, inp, out, hfin);
    ln_kernel<<<(BB * SS * NN) / 256, 256, 0, stream>>>(x, gamma_s, out);
}